// Round 1
// baseline (1049.716 us; speedup 1.0000x reference)
//
#include <hip/hip_runtime.h>

#define N_IN 128
#define HID 256
#define NB 16
#define BM 128
#define HS_STRIDE 264   // 256 + 8 bf16 pad: +4 bank shift per row -> conflict-free b128 reads
#define BS_STRIDE 17    // basis LDS stride (f32), breaks 16-stride bank aliasing

typedef __attribute__((ext_vector_type(8))) short s8v;   // 8 bf16 in 4 VGPRs
typedef __attribute__((ext_vector_type(4))) float f4v;   // MFMA 16x16x32 accumulator

__device__ __forceinline__ unsigned short f2bf(float f) {
  unsigned int u = __float_as_uint(f);
  u += 0x7fffu + ((u >> 16) & 1u);   // round-to-nearest-even
  return (unsigned short)(u >> 16);
}

__device__ __forceinline__ float tanh_fast(float x) {
  // tanh(x) = 1 - 2/(exp(2x)+1); exp overflow/underflow gives correct +-1 saturation
  float e = __expf(2.0f * x);
  return 1.0f - 2.0f * __builtin_amdgcn_rcpf(e + 1.0f);
}

// Repack weights to bf16, k-contiguous for MFMA B-fragments.
// W1r[n*128 + k]            = bf16(W1[k*256 + n])          (n in [0,256), k in [0,128))
// W2r[((b*128+c)*256) + k]  = bf16(W2[k*2048 + c*16 + b])  (b in [0,16), c in [0,128), k in [0,256))
__global__ void prep_kernel(const float* __restrict__ W1, const float* __restrict__ W2,
                            unsigned short* __restrict__ W1r, unsigned short* __restrict__ W2r) {
  int tid = blockIdx.x * blockDim.x + threadIdx.x;
  if (tid < N_IN * HID) {
    int n = tid >> 7, k = tid & 127;
    W1r[tid] = f2bf(W1[k * HID + n]);
  }
  int i = tid - N_IN * HID;
  if (i >= 0 && i < HID * (N_IN * NB)) {
    int k = i & 255, c = (i >> 8) & 127, b = i >> 15;
    W2r[i] = f2bf(W2[k * (N_IN * NB) + c * 16 + b]);
  }
}

__global__ void __launch_bounds__(256, 2)
pilayer_kernel(const float* __restrict__ prop,
               const int* __restrict__ idx_i,
               const int* __restrict__ idx_j,
               const float* __restrict__ basis,
               const unsigned short* __restrict__ W1r,
               const unsigned short* __restrict__ W2r,
               float* __restrict__ out, int P) {
  __shared__ unsigned short Hs[BM * HS_STRIDE];   // 67,584 B
  __shared__ float basisS[BM * BS_STRIDE];        //  8,704 B  -> 76.3 KB total, 2 blocks/CU

  const int t = threadIdx.x;
  const int lane = t & 63;
  const int wv = t >> 6;        // wave 0..3, owns local rows [32*wv, 32*wv+32)
  const int l15 = lane & 15;
  const int l4 = lane >> 4;     // 0..3
  const int tile0 = blockIdx.x * BM;
  const int row0 = wv * 32;

  // ---- stage basis tile (each wave stages exactly its own 32 rows -> no barrier) ----
  {
    int r = t >> 1;                    // local row 0..127
    int c0 = (t & 1) * 8;
    int p = tile0 + r; if (p >= P) p = P - 1;
    const float4* bp = (const float4*)(basis + (long)p * NB + c0);
    float4 b0 = bp[0], b1 = bp[1];
    float* dst = &basisS[r * BS_STRIDE + c0];
    dst[0] = b0.x; dst[1] = b0.y; dst[2] = b0.z; dst[3] = b0.w;
    dst[4] = b1.x; dst[5] = b1.y; dst[6] = b1.z; dst[7] = b1.w;
  }

  // preload gather indices for this wave's A-fragment rows (m = row0 + rt*16 + l15)
  int pidx[2], qidx[2];
#pragma unroll
  for (int rt = 0; rt < 2; ++rt) {
    int p = tile0 + row0 + rt * 16 + l15; if (p >= P) p = P - 1;
    pidx[rt] = idx_i[p];
    qidx[rt] = idx_j[p];
  }

  // ---- Phase B: H = tanh((prop[i]+prop[j]) @ W1), bf16 into LDS (wave-local rows) ----
#pragma unroll
  for (int pass = 0; pass < 2; ++pass) {
    f4v acc[2][8];
#pragma unroll
    for (int rt = 0; rt < 2; ++rt) {
#pragma unroll
      for (int ct = 0; ct < 8; ++ct) acc[rt][ct] = (f4v){0.f, 0.f, 0.f, 0.f};
    }
#pragma unroll
    for (int kk = 0; kk < 4; ++kk) {          // K = 128, step 32
      int k0 = kk * 32 + l4 * 8;
      s8v afr[2];
#pragma unroll
      for (int rt = 0; rt < 2; ++rt) {
        const float4* ai = (const float4*)(prop + (long)pidx[rt] * N_IN + k0);
        const float4* aj = (const float4*)(prop + (long)qidx[rt] * N_IN + k0);
        float4 x0 = ai[0], x1 = ai[1];
        float4 y0 = aj[0], y1 = aj[1];
        s8v a;
        a[0] = (short)f2bf(x0.x + y0.x); a[1] = (short)f2bf(x0.y + y0.y);
        a[2] = (short)f2bf(x0.z + y0.z); a[3] = (short)f2bf(x0.w + y0.w);
        a[4] = (short)f2bf(x1.x + y1.x); a[5] = (short)f2bf(x1.y + y1.y);
        a[6] = (short)f2bf(x1.z + y1.z); a[7] = (short)f2bf(x1.w + y1.w);
        afr[rt] = a;
      }
#pragma unroll
      for (int ct = 0; ct < 8; ++ct) {
        const s8v* wp = (const s8v*)(W1r + (pass * 128 + ct * 16 + l15) * N_IN + k0);
        s8v bfr = *wp;
#pragma unroll
        for (int rt = 0; rt < 2; ++rt)
          acc[rt][ct] = __builtin_amdgcn_mfma_f32_16x16x32_bf16(afr[rt], bfr, acc[rt][ct], 0, 0, 0);
      }
    }
    // tanh + bf16 store to Hs (C layout: row=(l4*4+r), col=l15 within 16x16 tile)
#pragma unroll
    for (int rt = 0; rt < 2; ++rt) {
#pragma unroll
      for (int ct = 0; ct < 8; ++ct) {
#pragma unroll
        for (int r = 0; r < 4; ++r) {
          int lrow = row0 + rt * 16 + l4 * 4 + r;
          int col = pass * 128 + ct * 16 + l15;
          Hs[lrow * HS_STRIDE + col] = f2bf(tanh_fast(acc[rt][ct][r]));
        }
      }
    }
  }
  // H rows read below are the same rows this wave wrote; compiler's lgkmcnt ordering suffices.

  // ---- Phase C: out[p][c] = sum_b basis[p][b] * (H @ W2[:, c*16+b])[p] ----
  f4v oacc[2][8];
#pragma unroll
  for (int rt = 0; rt < 2; ++rt) {
#pragma unroll
    for (int ct = 0; ct < 8; ++ct) oacc[rt][ct] = (f4v){0.f, 0.f, 0.f, 0.f};
  }

#pragma unroll 1
  for (int b = 0; b < NB; ++b) {
    f4v g[2][8];
#pragma unroll
    for (int rt = 0; rt < 2; ++rt) {
#pragma unroll
      for (int ct = 0; ct < 8; ++ct) g[rt][ct] = (f4v){0.f, 0.f, 0.f, 0.f};
    }
#pragma unroll
    for (int kk = 0; kk < 8; ++kk) {          // K = 256, step 32
      s8v afr[2];
#pragma unroll
      for (int rt = 0; rt < 2; ++rt) {
        const s8v* hp = (const s8v*)&Hs[(row0 + rt * 16 + l15) * HS_STRIDE + kk * 32 + l4 * 8];
        afr[rt] = *hp;
      }
#pragma unroll
      for (int ct = 0; ct < 8; ++ct) {
        const s8v* wp = (const s8v*)(W2r + ((b * 128 + ct * 16 + l15) * HID) + kk * 32 + l4 * 8);
        s8v bfr = *wp;
#pragma unroll
        for (int rt = 0; rt < 2; ++rt)
          g[rt][ct] = __builtin_amdgcn_mfma_f32_16x16x32_bf16(afr[rt], bfr, g[rt][ct], 0, 0, 0);
      }
    }
    // row-scale by basis[p][b] and accumulate (C layout: row = (lane>>4)*4 + reg)
#pragma unroll
    for (int rt = 0; rt < 2; ++rt) {
#pragma unroll
      for (int r = 0; r < 4; ++r) {
        float bs = basisS[(row0 + rt * 16 + l4 * 4 + r) * BS_STRIDE + b];
#pragma unroll
        for (int ct = 0; ct < 8; ++ct)
          oacc[rt][ct][r] += g[rt][ct][r] * bs;
      }
    }
  }

  // ---- epilogue: store out[p][c], c = ct*16 + l15 ----
#pragma unroll
  for (int rt = 0; rt < 2; ++rt) {
#pragma unroll
    for (int r = 0; r < 4; ++r) {
      int p = tile0 + row0 + rt * 16 + l4 * 4 + r;
      if (p < P) {
        float* op = out + (long)p * N_IN + l15;
#pragma unroll
        for (int ct = 0; ct < 8; ++ct)
          op[ct * 16] = oacc[rt][ct][r];
      }
    }
  }
}

extern "C" void kernel_launch(void* const* d_in, const int* in_sizes, int n_in,
                              void* d_out, int out_size, void* d_ws, size_t ws_size,
                              hipStream_t stream) {
  const float* prop  = (const float*)d_in[0];
  const int* idx_i   = (const int*)d_in[1];
  const int* idx_j   = (const int*)d_in[2];
  const float* basis = (const float*)d_in[3];
  const float* W1    = (const float*)d_in[4];
  const float* W2    = (const float*)d_in[5];
  float* out = (float*)d_out;
  int P = in_sizes[1];

  unsigned short* W1r = (unsigned short*)d_ws;                 // 32768 bf16
  unsigned short* W2r = W1r + N_IN * HID;                      // 524288 bf16

  int prep_threads = N_IN * HID + HID * N_IN * NB;             // 557056
  prep_kernel<<<(prep_threads + 255) / 256, 256, 0, stream>>>(W1, W2, W1r, W2r);

  int ntiles = (P + BM - 1) / BM;
  pilayer_kernel<<<ntiles, 256, 0, stream>>>(prop, idx_i, idx_j, basis, W1r, W2r, out, P);
}

// Round 2
// 726.484 us; speedup vs baseline: 1.4449x; 1.4449x over previous
//
#include <hip/hip_runtime.h>

#define N_IN 128
#define HID 256
#define NB 16
#define BM 128
#define HS_STRIDE 264   // 256 + 8 bf16 pad -> phase-C A reads are 2-way-bank (free)
#define BS_STRIDE 17    // basis LDS stride (f32)

typedef __attribute__((ext_vector_type(8))) short s8v;   // 8 bf16 in 4 VGPRs
typedef __attribute__((ext_vector_type(4))) float f4v;   // MFMA 16x16x32 accumulator

__device__ __forceinline__ unsigned short f2bf(float f) {
  unsigned int u = __float_as_uint(f);
  u += 0x7fffu + ((u >> 16) & 1u);   // round-to-nearest-even
  return (unsigned short)(u >> 16);
}

__device__ __forceinline__ float tanh_fast(float x) {
  float e = __expf(2.0f * x);
  return 1.0f - 2.0f * __builtin_amdgcn_rcpf(e + 1.0f);
}

// Repack weights to bf16 in MFMA *fragment order*: each fragment is 64 lanes x 16 B
// contiguous (1 KB), so a B-operand load is one fully-coalesced global_load_dwordx4.
// Fragment element (lane, j):  B[n = l15][k = (lane>>4)*8 + j]  within the tile.
// W1f frag id (pass, kk, ct):  n = pass*128 + ct*16 + l15, k = kk*32 + quad*8 + j,  val = W1[k*256 + n]
// W2f frag id (b, kk, ct):     n = ct*16 + l15,  k = kk*32 + quad*8 + j,            val = W2[k*2048 + n*16 + b]
__global__ void prep_kernel(const float* __restrict__ W1, const float* __restrict__ W2,
                            unsigned short* __restrict__ W1f, unsigned short* __restrict__ W2f) {
  int tid = blockIdx.x * blockDim.x + threadIdx.x;
  if (tid < N_IN * HID) {                     // 32768 W1 elements
    int j = tid & 7, lane = (tid >> 3) & 63, ct = (tid >> 9) & 7, kk = (tid >> 12) & 3, pass = tid >> 14;
    int n = pass * 128 + ct * 16 + (lane & 15);
    int k = kk * 32 + (lane >> 4) * 8 + j;
    W1f[tid] = f2bf(W1[k * HID + n]);
  }
  int i = tid - N_IN * HID;
  if (i >= 0 && i < HID * (N_IN * NB)) {      // 524288 W2 elements
    int j = i & 7, lane = (i >> 3) & 63, ct = (i >> 9) & 7, kk = (i >> 12) & 7, b = i >> 15;
    int n = ct * 16 + (lane & 15);
    int k = kk * 32 + (lane >> 4) * 8 + j;
    W2f[i] = f2bf(W2[k * (N_IN * NB) + n * 16 + b]);
  }
}

__global__ void __launch_bounds__(256, 2)
pilayer_kernel(const float* __restrict__ prop,
               const int* __restrict__ idx_i,
               const int* __restrict__ idx_j,
               const float* __restrict__ basis,
               const unsigned short* __restrict__ W1f,
               const unsigned short* __restrict__ W2f,
               float* __restrict__ out, int P) {
  __shared__ unsigned short Hs[BM * HS_STRIDE];   // 67,584 B
  __shared__ float basisS[BM * BS_STRIDE];        //  8,704 B  -> 76.3 KB, 2 blocks/CU

  const int t = threadIdx.x;
  const int lane = t & 63;
  const int wv = t >> 6;
  const int l15 = lane & 15;
  const int l4 = lane >> 4;
  const int tile0 = blockIdx.x * BM;

  // ---- stage basis tile cooperatively ----
  {
    int r = t >> 1;
    int c0 = (t & 1) * 8;
    int p = tile0 + r; if (p >= P) p = P - 1;
    const float4* bp = (const float4*)(basis + (long)p * NB + c0);
    float4 b0 = bp[0], b1 = bp[1];
    float* dst = &basisS[r * BS_STRIDE + c0];
    dst[0] = b0.x; dst[1] = b0.y; dst[2] = b0.z; dst[3] = b0.w;
    dst[4] = b1.x; dst[5] = b1.y; dst[6] = b1.z; dst[7] = b1.w;
  }

  // ---- Phase B: wave wv computes H rows [32*wv, 32*wv+32), all 256 cols ----
  {
    const int row0 = wv * 32;
    int pidx[2], qidx[2];
#pragma unroll
    for (int rt = 0; rt < 2; ++rt) {
      int p = tile0 + row0 + rt * 16 + l15; if (p >= P) p = P - 1;
      pidx[rt] = idx_i[p];
      qidx[rt] = idx_j[p];
    }
#pragma unroll
    for (int pass = 0; pass < 2; ++pass) {
      f4v acc[2][8];
#pragma unroll
      for (int rt = 0; rt < 2; ++rt)
#pragma unroll
        for (int ct = 0; ct < 8; ++ct) acc[rt][ct] = (f4v){0.f, 0.f, 0.f, 0.f};
#pragma unroll
      for (int kk = 0; kk < 4; ++kk) {        // K = 128, step 32
        int k0 = kk * 32 + l4 * 8;
        s8v afr[2];
#pragma unroll
        for (int rt = 0; rt < 2; ++rt) {
          const float4* ai = (const float4*)(prop + (long)pidx[rt] * N_IN + k0);
          const float4* aj = (const float4*)(prop + (long)qidx[rt] * N_IN + k0);
          float4 x0 = ai[0], x1 = ai[1];
          float4 y0 = aj[0], y1 = aj[1];
          s8v a;
          a[0] = (short)f2bf(x0.x + y0.x); a[1] = (short)f2bf(x0.y + y0.y);
          a[2] = (short)f2bf(x0.z + y0.z); a[3] = (short)f2bf(x0.w + y0.w);
          a[4] = (short)f2bf(x1.x + y1.x); a[5] = (short)f2bf(x1.y + y1.y);
          a[6] = (short)f2bf(x1.z + y1.z); a[7] = (short)f2bf(x1.w + y1.w);
          afr[rt] = a;
        }
#pragma unroll
        for (int ct = 0; ct < 8; ++ct) {
          const s8v* wp = (const s8v*)(W1f + ((((pass * 4 + kk) * 8 + ct) * 64 + lane) << 3));
          s8v bfr = *wp;
#pragma unroll
          for (int rt = 0; rt < 2; ++rt)
            acc[rt][ct] = __builtin_amdgcn_mfma_f32_16x16x32_bf16(afr[rt], bfr, acc[rt][ct], 0, 0, 0);
        }
      }
#pragma unroll
      for (int rt = 0; rt < 2; ++rt)
#pragma unroll
        for (int ct = 0; ct < 8; ++ct)
#pragma unroll
          for (int r = 0; r < 4; ++r) {
            int lrow = row0 + rt * 16 + l4 * 4 + r;
            int col = pass * 128 + ct * 16 + l15;
            Hs[lrow * HS_STRIDE + col] = f2bf(tanh_fast(acc[rt][ct][r]));
          }
    }
  }

  __syncthreads();   // H + basis now visible to all waves

  // ---- Phase C: 2x2 wave partition, each wave owns a 64x64 output tile per b ----
  const int rh = (wv >> 1) * 64;     // row offset of this wave's tile
  const int cq = (wv & 1) * 4;       // col-tile offset (x16 cols)

  f4v oacc[4][4];
#pragma unroll
  for (int rt = 0; rt < 4; ++rt)
#pragma unroll
    for (int ct = 0; ct < 4; ++ct) oacc[rt][ct] = (f4v){0.f, 0.f, 0.f, 0.f};

#pragma unroll 1
  for (int b = 0; b < NB; ++b) {
    f4v g[4][4];
#pragma unroll
    for (int rt = 0; rt < 4; ++rt)
#pragma unroll
      for (int ct = 0; ct < 4; ++ct) g[rt][ct] = (f4v){0.f, 0.f, 0.f, 0.f};
#pragma unroll
    for (int kk = 0; kk < 8; ++kk) {          // K = 256, step 32
      s8v afr[4];
#pragma unroll
      for (int rt = 0; rt < 4; ++rt)
        afr[rt] = *(const s8v*)&Hs[(rh + rt * 16 + l15) * HS_STRIDE + kk * 32 + l4 * 8];
      s8v bfr[4];
#pragma unroll
      for (int ct = 0; ct < 4; ++ct)
        bfr[ct] = *(const s8v*)(W2f + ((((b * 8 + kk) * 8 + cq + ct) * 64 + lane) << 3));
#pragma unroll
      for (int rt = 0; rt < 4; ++rt)
#pragma unroll
        for (int ct = 0; ct < 4; ++ct)
          g[rt][ct] = __builtin_amdgcn_mfma_f32_16x16x32_bf16(afr[rt], bfr[ct], g[rt][ct], 0, 0, 0);
    }
    // scale rows by basis[p][b], accumulate (C layout: row = l4*4 + reg within 16-tile)
#pragma unroll
    for (int rt = 0; rt < 4; ++rt)
#pragma unroll
      for (int r = 0; r < 4; ++r) {
        float bs = basisS[(rh + rt * 16 + l4 * 4 + r) * BS_STRIDE + b];
#pragma unroll
        for (int ct = 0; ct < 4; ++ct)
          oacc[rt][ct][r] += g[rt][ct][r] * bs;
      }
  }

  // ---- epilogue: out[p][c], c = (cq+ct)*16 + l15 ----
#pragma unroll
  for (int rt = 0; rt < 4; ++rt)
#pragma unroll
    for (int r = 0; r < 4; ++r) {
      int p = tile0 + rh + rt * 16 + l4 * 4 + r;
      if (p < P) {
        float* op = out + (long)p * N_IN + cq * 16 + l15;
#pragma unroll
        for (int ct = 0; ct < 4; ++ct)
          op[ct * 16] = oacc[rt][ct][r];
      }
    }
}

extern "C" void kernel_launch(void* const* d_in, const int* in_sizes, int n_in,
                              void* d_out, int out_size, void* d_ws, size_t ws_size,
                              hipStream_t stream) {
  const float* prop  = (const float*)d_in[0];
  const int* idx_i   = (const int*)d_in[1];
  const int* idx_j   = (const int*)d_in[2];
  const float* basis = (const float*)d_in[3];
  const float* W1    = (const float*)d_in[4];
  const float* W2    = (const float*)d_in[5];
  float* out = (float*)d_out;
  int P = in_sizes[1];

  unsigned short* W1f = (unsigned short*)d_ws;                 // 32768 bf16
  unsigned short* W2f = W1f + N_IN * HID;                      // 524288 bf16

  int prep_threads = N_IN * HID + HID * N_IN * NB;             // 557056
  prep_kernel<<<(prep_threads + 255) / 256, 256, 0, stream>>>(W1, W2, W1f, W2f);

  int ntiles = (P + BM - 1) / BM;
  pilayer_kernel<<<ntiles, 256, 0, stream>>>(prop, idx_i, idx_j, basis, W1f, W2f, out, P);
}